// Round 3
// baseline (211.373 us; speedup 1.0000x reference)
//
#include <hip/hip_runtime.h>
#include <math.h>

// Problem constants: B=8, T=16, P=197, C=1024, R=8
#define BB 8
#define TT 16
#define PP 197
#define CC 1024
#define RR 8
#define NROWS (BB * TT * PP)   // 25216 rows of (b,t,p)
#define NSEQ  (BB * PP)        // 1576 LSTM sequences
#define LORA_SCALE 2.0f        // alpha/rank = 16/8

__device__ __forceinline__ float sigf(float x) {
    x = fminf(fmaxf(x, -30.f), 30.f);
    return 1.0f / (1.0f + __expf(-x));
}
__device__ __forceinline__ float tanh_fast(float x) {
    x = fminf(fmaxf(x, -15.f), 15.f);
    float e = __expf(-2.0f * x);
    return (1.0f - e) / (1.0f + e);
}
__device__ __forceinline__ float dot4(const float4& a, const float4& b) {
    return a.x * b.x + a.y * b.y + a.z * b.z + a.w * b.w;
}

// ---------- Kernel 1: LoRA down.  red[row][r] = mask(b,t) * sum_c hs[row][c]*dw[r][c]
// One row per wave-iteration, software-pipelined: next row's 4 dwordx4 loads issue
// before the current row's FMAs/butterfly, so HBM latency (~900cyc) hides behind
// ~700cyc of compute. down_w register-resident (128 VGPR), 2 waves/SIMD guaranteed.
__global__ __launch_bounds__(256, 2) void k_down(const float* __restrict__ hs,
                                                 const float* __restrict__ dw,
                                                 const float* __restrict__ fm,
                                                 float* __restrict__ red) {
    const int lane = threadIdx.x & 63;
    const int wid  = (blockIdx.x * blockDim.x + threadIdx.x) >> 6;
    const int nw   = (gridDim.x * blockDim.x) >> 6;

    // preload down_w: 128 floats/lane, coalesced (lane-stride 16B)
    float4 w[RR][4];
#pragma unroll
    for (int r = 0; r < RR; ++r)
#pragma unroll
        for (int k = 0; k < 4; ++k)
            w[r][k] = *(const float4*)(dw + r * CC + k * 256 + lane * 4);

    int row = wid;
    if (row >= NROWS) return;

    float4 xc[4];
    {
        const float* rp = hs + (size_t)row * CC;
#pragma unroll
        for (int k = 0; k < 4; ++k) xc[k] = *(const float4*)(rp + k * 256 + lane * 4);
    }

    while (true) {
        const int nrow = row + nw;
        const bool has_next = (nrow < NROWS);
        float4 xn[4];
        if (has_next) {
            const float* rp = hs + (size_t)nrow * CC;
#pragma unroll
            for (int k = 0; k < 4; ++k) xn[k] = *(const float4*)(rp + k * 256 + lane * 4);
        }

        float acc[RR];
#pragma unroll
        for (int r = 0; r < RR; ++r) {
            float a = 0.f;
#pragma unroll
            for (int k = 0; k < 4; ++k) a += dot4(xc[k], w[r][k]);
            acc[r] = a;
        }
#pragma unroll
        for (int d = 32; d >= 1; d >>= 1) {
#pragma unroll
            for (int r = 0; r < RR; ++r) acc[r] += __shfl_xor(acc[r], d, 64);
        }
        if (lane == 0) {
            const float m = fm[row / PP];   // row/PP == b*T + t
            float4* op = (float4*)(red + (size_t)row * RR);
            op[0] = make_float4(acc[0] * m, acc[1] * m, acc[2] * m, acc[3] * m);
            op[1] = make_float4(acc[4] * m, acc[5] * m, acc[6] * m, acc[7] * m);
        }
        if (!has_next) break;
        row = nrow;
#pragma unroll
        for (int k = 0; k < 4; ++k) xc[k] = xn[k];
    }
}

// ---------- Kernel 2: rank-8 LSTM over T. 8 lanes per sequence; lane owns rank slot r.
__global__ __launch_bounds__(64) void k_lstm(const float* __restrict__ red,
                                             const float* __restrict__ fm,
                                             const float* __restrict__ w_ih,
                                             const float* __restrict__ w_hh,
                                             const float* __restrict__ b_ih,
                                             const float* __restrict__ b_hh,
                                             float* __restrict__ hsm) {
    const int tid = blockIdx.x * blockDim.x + threadIdx.x;
    const int n = tid >> 3;            // sequence index = b*P + p
    const int r = tid & 7;             // rank slot
    const int lane = threadIdx.x & 63;
    const int grp = lane & 56;
    if (n >= NSEQ) return;

    float wi_i[8], wi_f[8], wi_g[8], wi_o[8];
    float wh_i[8], wh_f[8], wh_g[8], wh_o[8];
#pragma unroll
    for (int j = 0; j < 8; ++j) {
        wi_i[j] = w_ih[(r) * 8 + j];
        wi_f[j] = w_ih[(8 + r) * 8 + j];
        wi_g[j] = w_ih[(16 + r) * 8 + j];
        wi_o[j] = w_ih[(24 + r) * 8 + j];
        wh_i[j] = w_hh[(r) * 8 + j];
        wh_f[j] = w_hh[(8 + r) * 8 + j];
        wh_g[j] = w_hh[(16 + r) * 8 + j];
        wh_o[j] = w_hh[(24 + r) * 8 + j];
    }
    const float bi = b_ih[r] + b_hh[r];
    const float bf = b_ih[8 + r] + b_hh[8 + r];
    const float bg = b_ih[16 + r] + b_hh[16 + r];
    const float bo = b_ih[24 + r] + b_hh[24 + r];

    const int b = n / PP, p = n - (n / PP) * PP;
    const size_t base = ((size_t)b * TT * PP + p) * RR + r;
    const size_t tstride = (size_t)PP * RR;

    float xs[TT], msk[TT];
#pragma unroll
    for (int t = 0; t < TT; ++t) xs[t] = red[base + (size_t)t * tstride];
#pragma unroll
    for (int t = 0; t < TT; ++t) msk[t] = fm[b * TT + t];

    float h = 0.f, c = 0.f;
#pragma unroll
    for (int t = 0; t < TT; ++t) {
        float gi = bi, gf = bf, gg = bg, go = bo;
#pragma unroll
        for (int j = 0; j < 8; ++j) {
            const float xv = __shfl(xs[t], grp + j, 64);
            const float hv = __shfl(h, grp + j, 64);
            gi += wi_i[j] * xv + wh_i[j] * hv;
            gf += wi_f[j] * xv + wh_f[j] * hv;
            gg += wi_g[j] * xv + wh_g[j] * hv;
            go += wi_o[j] * xv + wh_o[j] * hv;
        }
        c = sigf(gf) * c + sigf(gi) * tanh_fast(gg);
        h = sigf(go) * tanh_fast(c);
        hsm[base + (size_t)t * tstride] = h * msk[t];
    }
}

// ---------- Kernel 3: LoRA up.  out[row][c] = SCALE * sum_r hsm[row][r]*up[c][r]
// Lane owns cols {g*64 + lane}; up preload one-time per wave; h loads for the next
// row prefetched while the current row's 16 coalesced dword stores drain.
__global__ __launch_bounds__(256, 2) void k_up(const float* __restrict__ hsm,
                                               const float* __restrict__ up,
                                               float* __restrict__ out) {
    const int lane = threadIdx.x & 63;
    const int wid  = (blockIdx.x * blockDim.x + threadIdx.x) >> 6;
    const int nw   = (gridDim.x * blockDim.x) >> 6;

    float4 u0[16], u1[16];   // up rows for col = g*64 + lane
#pragma unroll
    for (int g = 0; g < 16; ++g) {
        const float* pp = up + (size_t)(g * 64 + lane) * RR;
        u0[g] = *(const float4*)(pp);
        u1[g] = *(const float4*)(pp + 4);
    }

    int row = wid;
    if (row >= NROWS) return;

    float4 h0 = *(const float4*)(hsm + (size_t)row * RR);
    float4 h1 = *(const float4*)(hsm + (size_t)row * RR + 4);

    while (true) {
        const int nrow = row + nw;
        const bool has_next = (nrow < NROWS);
        float4 n0, n1;
        if (has_next) {
            n0 = *(const float4*)(hsm + (size_t)nrow * RR);
            n1 = *(const float4*)(hsm + (size_t)nrow * RR + 4);
        }
        h0.x *= LORA_SCALE; h0.y *= LORA_SCALE; h0.z *= LORA_SCALE; h0.w *= LORA_SCALE;
        h1.x *= LORA_SCALE; h1.y *= LORA_SCALE; h1.z *= LORA_SCALE; h1.w *= LORA_SCALE;
        float* op = out + (size_t)row * CC + lane;
#pragma unroll
        for (int g = 0; g < 16; ++g) {
            op[g * 64] = dot4(h0, u0[g]) + dot4(h1, u1[g]);
        }
        if (!has_next) break;
        row = nrow;
        h0 = n0; h1 = n1;
    }
}

extern "C" void kernel_launch(void* const* d_in, const int* in_sizes, int n_in,
                              void* d_out, int out_size, void* d_ws, size_t ws_size,
                              hipStream_t stream) {
    const float* hs  = (const float*)d_in[0];  // (B,T,P,C)
    const float* fm  = (const float*)d_in[2];  // (B,T)
    const float* dw  = (const float*)d_in[3];  // (R,C)
    const float* wih = (const float*)d_in[4];  // (4R,R)
    const float* whh = (const float*)d_in[5];  // (4R,R)
    const float* bih = (const float*)d_in[6];  // (4R,)
    const float* bhh = (const float*)d_in[7];  // (4R,)
    const float* up  = (const float*)d_in[8];  // (C,R)
    float* out = (float*)d_out;

    float* red = (float*)d_ws;
    float* hsm = red + (size_t)NROWS * RR;

    // K1: 1024 blocks x 4 waves = 4096 waves, ~6 rows each, pipelined
    k_down<<<1024, 256, 0, stream>>>(hs, dw, fm, red);
    // K2: 197 blocks x 64 threads = exactly NSEQ*8 lanes
    k_lstm<<<197, 64, 0, stream>>>(red, fm, wih, whh, bih, bhh, hsm);
    // K3: 1024 blocks x 4 waves, ~6 rows per wave, h prefetched
    k_up<<<1024, 256, 0, stream>>>(hsm, up, out);
}

// Round 4
// 208.468 us; speedup vs baseline: 1.0139x; 1.0139x over previous
//
#include <hip/hip_runtime.h>
#include <math.h>

// Problem constants: B=8, T=16, P=197, C=1024, R=8
#define BB 8
#define TT 16
#define PP 197
#define CC 1024
#define RR 8
#define NSEQ  (BB * PP)        // 1576 LSTM sequences, one wave each
#define LORA_SCALE 2.0f        // alpha/rank = 16/8

__device__ __forceinline__ float sigf(float x) {
    x = fminf(fmaxf(x, -30.f), 30.f);
    return 1.0f / (1.0f + __expf(-x));
}
__device__ __forceinline__ float tanh_fast(float x) {
    x = fminf(fmaxf(x, -15.f), 15.f);
    float e = __expf(-2.0f * x);
    return (1.0f - e) / (1.0f + e);
}
__device__ __forceinline__ float dot4(const float4& a, const float4& b) {
    return a.x * b.x + a.y * b.y + a.z * b.z + a.w * b.w;
}

// ---------------------------------------------------------------------------
// Fully fused: one 64-lane wave owns one (b,p) sequence end-to-end.
//   Phase 1 (down): 16 rows x 4KB coalesced loads, down_w register-resident
//                   (lane owns cols k*256+lane*4), butterfly-reduce, -> LDS.
//   Phase 2 (LSTM): 16 serial steps; lane r owns rank slot r (octets redundant);
//                   x broadcast from LDS, h via constant-lane shfl.
//   Phase 3 (up):   up_w register-resident (lane owns cols g*64+lane),
//                   h broadcast from LDS, 16 coalesced dword stores per row.
// No intermediate global traffic; no inter-wave communication at all.
// ---------------------------------------------------------------------------
__global__ __launch_bounds__(64, 2) void k_fused(const float* __restrict__ hs,
                                                 const float* __restrict__ fm,
                                                 const float* __restrict__ dw,
                                                 const float* __restrict__ w_ih,
                                                 const float* __restrict__ w_hh,
                                                 const float* __restrict__ b_ih,
                                                 const float* __restrict__ b_hh,
                                                 const float* __restrict__ up,
                                                 float* __restrict__ out) {
    __shared__ float red_lds[TT][RR];   // masked down-projection, per-wave private
    __shared__ float h_lds[TT][RR];     // masked+scaled hidden states

    const int lane = threadIdx.x;       // 64-thread block = exactly one wave
    const int seq  = blockIdx.x;        // 1576 blocks = NSEQ
    const int b = seq / PP;
    const int p = seq - b * PP;
    const float* hsbase = hs + ((size_t)b * TT * PP + p) * CC;  // t-stride = PP*CC

    // ---- Phase 1: LoRA down ----
    {
        float4 wreg[RR][4];
#pragma unroll
        for (int r = 0; r < RR; ++r)
#pragma unroll
            for (int k = 0; k < 4; ++k)
                wreg[r][k] = *(const float4*)(dw + r * CC + k * 256 + lane * 4);

        // 4-row software pipeline: ~830cyc of compute between issue and use
        float4 buf[4][4];
#pragma unroll
        for (int t = 0; t < 4; ++t) {
            const float* rp = hsbase + (size_t)t * PP * CC;
#pragma unroll
            for (int k = 0; k < 4; ++k) buf[t][k] = *(const float4*)(rp + k * 256 + lane * 4);
        }
#pragma unroll
        for (int t = 0; t < TT; ++t) {
            const int s = t & 3;
            float acc[RR];
#pragma unroll
            for (int r = 0; r < RR; ++r) {
                float a = 0.f;
#pragma unroll
                for (int k = 0; k < 4; ++k) a += dot4(buf[s][k], wreg[r][k]);
                acc[r] = a;
            }
            if (t + 4 < TT) {           // refill the slot just consumed
                const float* rp = hsbase + (size_t)(t + 4) * PP * CC;
#pragma unroll
                for (int k = 0; k < 4; ++k) buf[s][k] = *(const float4*)(rp + k * 256 + lane * 4);
            }
#pragma unroll
            for (int d = 32; d >= 1; d >>= 1)
#pragma unroll
                for (int r = 0; r < RR; ++r) acc[r] += __shfl_xor(acc[r], d, 64);
            if (lane == 0) {
                const float m = fm[b * TT + t];
                *(float4*)&red_lds[t][0] = make_float4(acc[0] * m, acc[1] * m, acc[2] * m, acc[3] * m);
                *(float4*)&red_lds[t][4] = make_float4(acc[4] * m, acc[5] * m, acc[6] * m, acc[7] * m);
            }
        }
    }

    // ---- Phase 2: rank-8 LSTM, 16 serial steps (octets compute redundantly) ----
    {
        const int r = lane & 7;
        float wi[4][8], wh[4][8];       // gate order i,f,g,o ; lane owns row g*8+r
#pragma unroll
        for (int g = 0; g < 4; ++g)
#pragma unroll
            for (int j = 0; j < 8; ++j) {
                wi[g][j] = w_ih[(g * 8 + r) * 8 + j];
                wh[g][j] = w_hh[(g * 8 + r) * 8 + j];
            }
        const float bi = b_ih[r]      + b_hh[r];
        const float bf = b_ih[8 + r]  + b_hh[8 + r];
        const float bg = b_ih[16 + r] + b_hh[16 + r];
        const float bo = b_ih[24 + r] + b_hh[24 + r];

        float h = 0.f, c = 0.f;
#pragma unroll
        for (int t = 0; t < TT; ++t) {
            const float4 x0 = *(const float4*)&red_lds[t][0];   // broadcast read
            const float4 x1 = *(const float4*)&red_lds[t][4];
            float gi = bi, gf = bf, gg = bg, go = bo;
            const float xs[8] = {x0.x, x0.y, x0.z, x0.w, x1.x, x1.y, x1.z, x1.w};
#pragma unroll
            for (int j = 0; j < 8; ++j) {
                const float hv = __shfl(h, j, 64);   // constant-lane broadcast
                gi += wi[0][j] * xs[j] + wh[0][j] * hv;
                gf += wi[1][j] * xs[j] + wh[1][j] * hv;
                gg += wi[2][j] * xs[j] + wh[2][j] * hv;
                go += wi[3][j] * xs[j] + wh[3][j] * hv;
            }
            c = sigf(gf) * c + sigf(gi) * tanh_fast(gg);
            h = sigf(go) * tanh_fast(c);
            if (lane < 8) h_lds[t][lane] = h * fm[b * TT + t] * LORA_SCALE;
        }
    }

    // ---- Phase 3: LoRA up ----
    {
        float4 u0[16], u1[16];          // up rows for col = g*64 + lane (reuses wreg's VGPRs)
#pragma unroll
        for (int g = 0; g < 16; ++g) {
            const float* pp = up + (size_t)(g * 64 + lane) * RR;
            u0[g] = *(const float4*)(pp);
            u1[g] = *(const float4*)(pp + 4);
        }
        float* obase = out + ((size_t)b * TT * PP + p) * CC + lane;
#pragma unroll
        for (int t = 0; t < TT; ++t) {
            const float4 h0 = *(const float4*)&h_lds[t][0];     // broadcast read
            const float4 h1 = *(const float4*)&h_lds[t][4];
            float* op = obase + (size_t)t * PP * CC;
#pragma unroll
            for (int g = 0; g < 16; ++g)
                op[g * 64] = dot4(h0, u0[g]) + dot4(h1, u1[g]);
        }
    }
}

extern "C" void kernel_launch(void* const* d_in, const int* in_sizes, int n_in,
                              void* d_out, int out_size, void* d_ws, size_t ws_size,
                              hipStream_t stream) {
    const float* hs  = (const float*)d_in[0];  // (B,T,P,C)
    const float* fm  = (const float*)d_in[2];  // (B,T)
    const float* dw  = (const float*)d_in[3];  // (R,C)
    const float* wih = (const float*)d_in[4];  // (4R,R)
    const float* whh = (const float*)d_in[5];  // (4R,R)
    const float* bih = (const float*)d_in[6];  // (4R,)
    const float* bhh = (const float*)d_in[7];  // (4R,)
    const float* up  = (const float*)d_in[8];  // (C,R)
    float* out = (float*)d_out;

    // One wave per sequence; 1576 single-wave blocks spread ~6.2 waves/CU.
    k_fused<<<NSEQ, 64, 0, stream>>>(hs, fm, dw, wih, whh, bih, bhh, up, out);
}